// Round 28
// baseline (236.854 us; speedup 1.0000x reference)
//
#include <hip/hip_runtime.h>

// Qwen3 attention block, MI355X gfx950.
// Sizes fixed by the reference: B=2, L=2048, D=2048, H=16, KVH=4, HD=128.
// Pipeline r28: cast -> QKV GEMM with FUSED RMSNorm+RoPE+V^T epilogue ->
//               causal flash attention (bf16 MFMA) -> output GEMM (f32 out).
//
// Champion r26/r27: 197.8/199.0us. Flash v15 73.7us stable. r28 (this):
// prep fused into QKV GEMM epilogue - the 128-wide N-tile == one head, so
// the norm axis is the block's column axis. Kills the QKVb round trip
// (GEMM 25MB write + prep 25MB read = 50MB ~ 8us) + prep launch. acc ->
// LDS bf16 (same values prep read) -> per-wave 4-row-chunk batched
// butterfly (VGPR-capped: 8-wave occupancy needs <=64) -> RoPE -> direct
// Q/K/V stores (V sigma32-permuted). RMSNorm now from f32 acc (closer to
// ref). WO GEMM untouched, separate kernel.
// Flash ladder: v7 100 -> v10 98.6 -> v11 KT=32 86.4 -> v13 XCD 82.4
// (FETCH 33.9->12.3MB) -> v14 RTZ 79.5 -> v15 1-ballot 73.7us.
// Closed: GEMM sync-structure (r13/r16), GEMM locality (r23 neutral),
// flash swizzle (b128 floor), V-from-global (r10), 32q/wave (r11),
// cvt_pk (r19/r20: no builtin, raw asm NaN).
// HARD RULE: NEVER add a min-waves launch_bounds arg (r4/r7 force-spill).

#define SEQL 2048
#define DMODEL 2048
#define NH 16
#define NKVH 4
#define HDIM 128
#define SCALE_QK 0.08838834764831845f  // 1/sqrt(128)
#define LOG2E 1.4426950408889634f      // folded into Q so softmax uses exp2
#define INFF 3.0e38f

typedef __attribute__((ext_vector_type(8))) short bf16x8;
typedef __attribute__((ext_vector_type(4))) float f32x4;
typedef __attribute__((ext_vector_type(4))) unsigned int u32x4;

__device__ __forceinline__ unsigned short f2bf(float x) {
  union { float f; unsigned u; } v; v.f = x;
  unsigned r = v.u + 0x7fffu + ((v.u >> 16) & 1u);  // RNE
  return (unsigned short)(r >> 16);
}
__device__ __forceinline__ float bf2f(unsigned short u) {
  union { unsigned u; float f; } v; v.u = ((unsigned)u) << 16;
  return v.f;
}

// ---------------- f32 -> bf16 cast, 8 elems/thread ----------------
__global__ __launch_bounds__(256) void cast_kernel(const float* __restrict__ src,
                                                   unsigned short* __restrict__ dst,
                                                   int n8) {
  int i = blockIdx.x * 256 + threadIdx.x;
  if (i >= n8) return;
  const f32x4* s4 = (const f32x4*)src;
  f32x4 a = s4[2 * i], b = s4[2 * i + 1];
  union { unsigned short s[8]; u32x4 v; } o;
  o.s[0] = f2bf(a[0]); o.s[1] = f2bf(a[1]); o.s[2] = f2bf(a[2]); o.s[3] = f2bf(a[3]);
  o.s[4] = f2bf(b[0]); o.s[5] = f2bf(b[1]); o.s[6] = f2bf(b[2]); o.s[7] = f2bf(b[3]);
  ((u32x4*)dst)[i] = o.v;
}

// three sources -> one contiguous bf16 dst (wq|wk|wv), saves 2 launches
__global__ __launch_bounds__(256) void cast3_kernel(const float* __restrict__ s0,
                                                    const float* __restrict__ s1,
                                                    const float* __restrict__ s2,
                                                    unsigned short* __restrict__ dst,
                                                    int n0, int n1, int n2) {
  int i = blockIdx.x * 256 + threadIdx.x;  // units of 8 elems
  const float* src;
  int j;
  if (i < n0) { src = s0; j = i; }
  else if (i < n0 + n1) { src = s1; j = i - n0; }
  else if (i < n0 + n1 + n2) { src = s2; j = i - n0 - n1; }
  else return;
  const f32x4* s4 = (const f32x4*)src;
  f32x4 a = s4[2 * j], b = s4[2 * j + 1];
  union { unsigned short s[8]; u32x4 v; } o;
  o.s[0] = f2bf(a[0]); o.s[1] = f2bf(a[1]); o.s[2] = f2bf(a[2]); o.s[3] = f2bf(a[3]);
  o.s[4] = f2bf(b[0]); o.s[5] = f2bf(b[1]); o.s[6] = f2bf(b[2]); o.s[7] = f2bf(b[3]);
  ((u32x4*)dst)[i] = o.v;
}

// ---------------- QKV GEMM with fused prep epilogue (r28) ----------------
// r26 8-wave structure: 128x128 tile, BK=64, 2-barrier/K-tile, both-sides
// swizzle, 32KB LDS (flat S[]: A = S[0..8K), B = S[8K..16K) in bf16 elems),
// 512 thr / 8 waves (2x4, 64x32 per wave), XCD-chunked grid (nx=24, chunk=3).
// Epilogue: acc -> S as bf16 C-tile [128][128] -> per-wave rows [16w,16w+16)
// in 4-row chunks: full-wave butterfly sum-of-squares (lane d holds cols
// d, d+64) -> RMSNorm+RoPE (Q pre-scaled SCALE_QK*LOG2E) or V sigma32-
// permuted transpose -> direct global stores. bx 0..15 = Q head, 16..19 =
// K head, 20..23 = V head (128-wide tiles == heads).
__global__ __launch_bounds__(512) void gemm_qkv_fused(
    const unsigned short* __restrict__ A,   // Xb (B*L, D) bf16
    const unsigned short* __restrict__ B,   // Wqkvb (3072, D) bf16
    const float* __restrict__ cosb,
    const float* __restrict__ sinb,
    const float* __restrict__ qw,
    const float* __restrict__ kw,
    unsigned short* __restrict__ Qb,        // (B,NH,L,HD)
    unsigned short* __restrict__ Kb,        // (B,NKVH,L,HD)
    unsigned short* __restrict__ Vtb) {     // (B,NKVH,HD,L) k-permuted
  __shared__ unsigned short S[128 * 128];   // 32KB: staging (A|B), then C-tile
  unsigned short* As = S;                   // 128x64 bf16 (16KB)
  unsigned short* Bs = S + 128 * 64;        // 128x64 bf16 (16KB)
  const int K = DMODEL, N = 3072;
  int tid = threadIdx.x;
  int w = tid >> 6, lane = tid & 63;
  int lr = lane & 15, lg = lane >> 4;
  // XCD-chunked bijection: nx=24, chunk=3
  int lid = (int)blockIdx.x + (int)blockIdx.y * 24;
  int xcd = lid & 7;
  int local = lid >> 3;
  int bx = 3 * xcd + local % 3;
  int by = local / 3;
  int m0 = by * 128, n0 = bx * 128;
  int wr = (w >> 2) * 64, wc = (w & 3) * 32;  // 2x4 wave grid, 64x32 per wave
  f32x4 zero4 = {0.f, 0.f, 0.f, 0.f};
  f32x4 acc[4][2];
  for (int i = 0; i < 4; ++i)
    for (int j = 0; j < 2; ++j) acc[i][j] = zero4;

  for (int k0 = 0; k0 < K; k0 += 64) {
    __syncthreads();  // all waves done reading previous tile
    for (int i = 0; i < 2; ++i) {
      int o = i * 8192 + tid * 16;              // linear byte offset in 16KB tile
      int row = o >> 7, cb = o & 127;           // 128B per row of 64 bf16
      int scb = cb ^ ((row & 7) << 4);          // inverse-swizzled source col
      const char* ga = (const char*)(A + (size_t)(m0 + row) * K + k0) + scb;
      const char* gb = (const char*)(B + (size_t)(n0 + row) * K + k0) + scb;
      __builtin_amdgcn_global_load_lds(
          (const __attribute__((address_space(1))) void*)ga,
          (__attribute__((address_space(3))) void*)((char*)As + i * 8192 + w * 1024),
          16, 0, 0);
      __builtin_amdgcn_global_load_lds(
          (const __attribute__((address_space(1))) void*)gb,
          (__attribute__((address_space(3))) void*)((char*)Bs + i * 8192 + w * 1024),
          16, 0, 0);
    }
    asm volatile("s_waitcnt vmcnt(0)" ::: "memory");
    __syncthreads();

    for (int kk = 0; kk < 2; ++kk) {
      bf16x8 a[4], b[2];
      for (int i = 0; i < 4; ++i) {
        int row = wr + i * 16 + lr;
        int col = kk * 64 + lg * 16;  // byte col within row
        a[i] = *(const bf16x8*)((const char*)As + row * 128 + (col ^ ((row & 7) << 4)));
      }
      for (int j = 0; j < 2; ++j) {
        int row = wc + j * 16 + lr;
        int col = kk * 64 + lg * 16;
        b[j] = *(const bf16x8*)((const char*)Bs + row * 128 + (col ^ ((row & 7) << 4)));
      }
      for (int i = 0; i < 4; ++i)
        for (int j = 0; j < 2; ++j)
          acc[i][j] = __builtin_amdgcn_mfma_f32_16x16x32_bf16(a[i], b[j], acc[i][j], 0, 0, 0);
    }
  }

  // ---- fused prep epilogue ----
  __syncthreads();  // staging reads done; reuse S as C-tile [128][128] bf16
  // C/D layout: col = lane&15, row = (lane>>4)*4 + reg (verified m89/m91)
  for (int i = 0; i < 4; ++i)
    for (int j = 0; j < 2; ++j) {
      int rl = wr + i * 16 + lg * 4;
      int cl = wc + j * 16 + lr;
      for (int r = 0; r < 4; ++r)
        S[(rl + r) * 128 + cl] = f2bf(acc[i][j][r]);
    }
  __syncthreads();

  int head = bx;          // 0..15 Q, 16..19 K, 20..23 V (tile == head)
  int b_ = m0 >> 11;      // batch; constant per block (2048 % 128 == 0)
  int d = lane;           // lane handles cols d and d+64
  float w0 = 0.f, w1 = 0.f;
  if (head < 16)      { w0 = qw[d]; w1 = qw[d + 64]; }
  else if (head < 20) { w0 = kw[d]; w1 = kw[d + 64]; }
  const float qscale = SCALE_QK * LOG2E;

  // wave w owns local rows [16w, 16w+16), processed in 4-row chunks (VGPR cap)
  for (int c4 = 0; c4 < 4; ++c4) {
    if (head < 20) {
      float x0[4], x1[4], ss[4];
#pragma unroll
      for (int rr = 0; rr < 4; ++rr) {
        int rl = 16 * w + c4 * 4 + rr;
        x0[rr] = bf2f(S[rl * 128 + d]);
        x1[rr] = bf2f(S[rl * 128 + d + 64]);
        ss[rr] = x0[rr] * x0[rr] + x1[rr] * x1[rr];
      }
#pragma unroll
      for (int m = 1; m < 64; m <<= 1) {
#pragma unroll
        for (int rr = 0; rr < 4; ++rr) ss[rr] += __shfl_xor(ss[rr], m);
      }
#pragma unroll
      for (int rr = 0; rr < 4; ++rr) {
        int rl = 16 * w + c4 * 4 + rr;
        int row = m0 + rl;              // = b_*2048 + l
        size_t crow = (size_t)row * HDIM;
        float c0 = cosb[crow + d], c1 = cosb[crow + d + 64];
        float s0 = sinb[crow + d], s1 = sinb[crow + d + 64];
        float inv = rsqrtf(ss[rr] * (1.0f / 128.0f) + 1e-6f);
        float n0v = x0[rr] * inv * w0, n1v = x1[rr] * inv * w1;
        float r0 = n0v * c0 - n1v * s0;
        float r1 = n1v * c1 + n0v * s1;
        int l = row & 2047;
        if (head < 16) {
          unsigned short* dst = Qb + (((size_t)(b_ * NH + head)) * SEQL + l) * HDIM;
          dst[d] = f2bf(r0 * qscale);
          dst[d + 64] = f2bf(r1 * qscale);
        } else {
          unsigned short* dst = Kb + (((size_t)(b_ * NKVH + head - 16)) * SEQL + l) * HDIM;
          dst[d] = f2bf(r0);
          dst[d + 64] = f2bf(r1);
        }
      }
    } else {
      // V: no norm/rope; sigma32-permuted transpose store (matches flash P-pack)
#pragma unroll
      for (int rr = 0; rr < 4; ++rr) {
        int rl = 16 * w + c4 * 4 + rr;
        int row = m0 + rl;
        int l = row & 2047;
        int lt = l & 31, lb = l & ~31;
        int lp = lb + 2 * (lt & 15) + (lt >> 4);  // sigma32(local k)
        unsigned short v0 = S[rl * 128 + d];
        unsigned short v1 = S[rl * 128 + d + 64];
        unsigned short* dst = Vtb + ((size_t)(b_ * NKVH + head - 20) * HDIM) * SEQL;
        dst[(size_t)d * SEQL + lp] = v0;
        dst[(size_t)(d + 64) * SEQL + lp] = v1;
      }
    }
  }
}

// ---------------- WO GEMM: C[M,N] = A[M,K] * B[N,K]^T, f32 out ----------------
// r26 8-wave structure + r23 XCD-chunk (nx = N/128 divisible by 8).
__global__ __launch_bounds__(512) void gemm_wo(const unsigned short* __restrict__ A,
                                               const unsigned short* __restrict__ B,
                                               float* __restrict__ C,
                                               int M, int N, int K) {
  __shared__ unsigned short As[128 * 64];  // 16KB, linear dest for global_load_lds
  __shared__ unsigned short Bs[128 * 64];  // 16KB
  int tid = threadIdx.x;
  int w = tid >> 6, lane = tid & 63;
  int lr = lane & 15, lg = lane >> 4;
  int nx = N >> 7;
  int lid = (int)blockIdx.x + (int)blockIdx.y * nx;
  int chunk = nx >> 3;
  int xcd = lid & 7;
  int local = lid >> 3;
  int bx = chunk * xcd + local % chunk;
  int by = local / chunk;
  int m0 = by * 128, n0 = bx * 128;
  int wr = (w >> 2) * 64, wc = (w & 3) * 32;  // 2x4 wave grid, 64x32 per wave
  f32x4 zero4 = {0.f, 0.f, 0.f, 0.f};
  f32x4 acc[4][2];
  for (int i = 0; i < 4; ++i)
    for (int j = 0; j < 2; ++j) acc[i][j] = zero4;

  for (int k0 = 0; k0 < K; k0 += 64) {
    __syncthreads();
    for (int i = 0; i < 2; ++i) {
      int o = i * 8192 + tid * 16;
      int row = o >> 7, cb = o & 127;
      int scb = cb ^ ((row & 7) << 4);
      const char* ga = (const char*)(A + (size_t)(m0 + row) * K + k0) + scb;
      const char* gb = (const char*)(B + (size_t)(n0 + row) * K + k0) + scb;
      __builtin_amdgcn_global_load_lds(
          (const __attribute__((address_space(1))) void*)ga,
          (__attribute__((address_space(3))) void*)((char*)As + i * 8192 + w * 1024),
          16, 0, 0);
      __builtin_amdgcn_global_load_lds(
          (const __attribute__((address_space(1))) void*)gb,
          (__attribute__((address_space(3))) void*)((char*)Bs + i * 8192 + w * 1024),
          16, 0, 0);
    }
    asm volatile("s_waitcnt vmcnt(0)" ::: "memory");
    __syncthreads();

    for (int kk = 0; kk < 2; ++kk) {
      bf16x8 a[4], b[2];
      for (int i = 0; i < 4; ++i) {
        int row = wr + i * 16 + lr;
        int col = kk * 64 + lg * 16;
        a[i] = *(const bf16x8*)((const char*)As + row * 128 + (col ^ ((row & 7) << 4)));
      }
      for (int j = 0; j < 2; ++j) {
        int row = wc + j * 16 + lr;
        int col = kk * 64 + lg * 16;
        b[j] = *(const bf16x8*)((const char*)Bs + row * 128 + (col ^ ((row & 7) << 4)));
      }
      for (int i = 0; i < 4; ++i)
        for (int j = 0; j < 2; ++j)
          acc[i][j] = __builtin_amdgcn_mfma_f32_16x16x32_bf16(a[i], b[j], acc[i][j], 0, 0, 0);
    }
  }

  for (int i = 0; i < 4; ++i)
    for (int j = 0; j < 2; ++j) {
      int row = m0 + wr + i * 16 + lg * 4;
      int col = n0 + wc + j * 16 + lr;
      for (int r = 0; r < 4; ++r)
        C[(size_t)(row + r) * N + col] = acc[i][j][r];
    }
}

// ---------------- causal flash attention, v15 (CHAMPION, 73.7us) -------------
// KT=32 dbuf, ONE barrier/tile, T14 prefetch, zero-crosslane common-path
// softmax, exp2 + T13 THR=8, T2 swizzle, setprio, RTZ P-pack, 1-ballot
// defer-max gate, LDS 40KB, XCD-chunked grid (FETCH 12.3MB).
// NO min-waves hint ever (r4/r7 force-spills).
__global__ __launch_bounds__(512) void flash_kernel(const unsigned short* __restrict__ Qb,
                                                    const unsigned short* __restrict__ Kb,
                                                    const unsigned short* __restrict__ Vtb,
                                                    unsigned short* __restrict__ AOb)
{
  __shared__ unsigned short Ks[2][32 * 128];   // [buf][k][d], swizzled (8KB each)
  __shared__ unsigned short Vs[2][128 * 32];   // [buf][hd][k-slot], swizzled (8KB each)
  __shared__ unsigned short Ps[128 * 32];      // [q][k-slot], swizzled (8KB)

  int tid = threadIdx.x, w = tid >> 6, lane = tid & 63;
  int lr = lane & 15, lg = lane >> 4;
  int lid = (int)blockIdx.x + ((int)blockIdx.y << 4);  // 0..511
  int work = ((lid & 7) << 6) | (lid >> 3);            // XCD-chunked bijection
  int bh = work >> 4;
  int xi = work & 15;
  int qt = ((work >> 5) & 1) ? 15 - xi : xi;           // anti-correlated pairs
  int b = bh >> 4, h = bh & 15, hk = h >> 2;  // GROUPS=4
  int q0 = qt * 128;
  int qrow_base = 16 * w + lg * 4;

  // Q fragments: wave-private 16 rows, held in registers
  const unsigned short* Qg =
      Qb + (((size_t)(b * NH + h)) * SEQL + q0 + 16 * w + lr) * HDIM + lg * 8;
  bf16x8 aq[4];
  for (int kk = 0; kk < 4; ++kk) aq[kk] = *(const bf16x8*)(Qg + kk * 32);

  const unsigned short* Kg0 = Kb + ((size_t)(b * NKVH + hk)) * SEQL * HDIM;
  const unsigned short* Vg0 = Vtb + ((size_t)(b * NKVH + hk)) * HDIM * SEQL;

  float m_run[4], l_part[4];
  f32x4 zero4 = {0.f, 0.f, 0.f, 0.f};
  f32x4 o_acc[8];
  for (int r = 0; r < 4; ++r) { m_run[r] = -INFF; l_part[r] = 0.f; }
  for (int f = 0; f < 8; ++f) o_acc[f] = zero4;

  int nt = 4 * (qt + 1);  // 32-key tiles; always multiple of 4 (even)

  // reg staging: 1x16B K + 1x16B V per thread per tile (512 thr x 16B = 8KB)
  u32x4 kr, vr;

  auto load_tile = [&](int tt) {
    int k0n = tt * 32;
    int o = tid * 16;
    kr = *(const u32x4*)((const char*)Kg0 + (size_t)(k0n + (o >> 8)) * 256 + (o & 255));
    vr = *(const u32x4*)((const char*)Vg0 +
                         (size_t)(o >> 6) * (SEQL * 2) + (size_t)k0n * 2 + (o & 63));
  };
  auto stage_tile = [&](char* kb, char* vb) {
    int o = tid * 16;
    int krow = o >> 8;
    *(u32x4*)(kb + (o ^ ((krow & 7) << 4))) = kr;
    int vrow = o >> 6;
    *(u32x4*)(vb + (o ^ ((vrow & 7) << 4))) = vr;
  };
  auto compute_tile = [&](int t, const char* kb, const char* vb) {
    int k0 = t * 32;
    if (k0 > q0 + 16 * w + 15) return;  // fully masked for this wave
    bool needmask = (k0 + 31 > q0 + 16 * w);

    // S = Q K^T  (s[j][r] = S[q=qrow_base+r][k = 16j+lr])
    f32x4 s[2];
    for (int j = 0; j < 2; ++j) s[j] = zero4;
    __builtin_amdgcn_s_setprio(1);
    for (int kk = 0; kk < 4; ++kk)
      for (int j = 0; j < 2; ++j) {
        int row = j * 16 + lr;
        bf16x8 bk = *(const bf16x8*)(kb +
                     ((row * 256 + kk * 64 + lg * 16) ^ ((lr & 7) << 4)));
        s[j] = __builtin_amdgcn_mfma_f32_16x16x32_bf16(aq[kk], bk, s[j], 0, 0, 0);
      }
    __builtin_amdgcn_s_setprio(0);

    // online softmax, exp2 domain. Masked values, per-row local maxima.
    float v0a[4], v1a[4], mxl[4];
    float gmax = -INFF;
    for (int r = 0; r < 4; ++r) {
      if (needmask) {
        int qg = q0 + qrow_base + r;
        v0a[r] = (k0 + lr <= qg) ? s[0][r] : -INFF;
        v1a[r] = (k0 + 16 + lr <= qg) ? s[1][r] : -INFF;
      } else {
        v0a[r] = s[0][r];
        v1a[r] = s[1][r];
      }
      mxl[r] = fmaxf(v0a[r], v1a[r]);
      gmax = fmaxf(gmax, mxl[r] - m_run[r]);  // growth, per lane, max over rows
    }
    // ONE wave-wide ballot per tile; rescale body self-corrects per row
    if (!__all(gmax <= 8.f)) {  // rare: some row grew > THR
      for (int r = 0; r < 4; ++r) {
        float mx = mxl[r];
        mx = fmaxf(mx, __shfl_xor(mx, 1));
        mx = fmaxf(mx, __shfl_xor(mx, 2));
        mx = fmaxf(mx, __shfl_xor(mx, 4));
        mx = fmaxf(mx, __shfl_xor(mx, 8));
        float m_new = fmaxf(m_run[r], mx);
        float sc = __builtin_amdgcn_exp2f(m_run[r] - m_new);
        l_part[r] *= sc;
        for (int f = 0; f < 8; ++f) o_acc[f][r] *= sc;
        m_run[r] = m_new;
      }
    }
    for (int r = 0; r < 4; ++r) {
      int qrow = qrow_base + r;
      float m_use = m_run[r];
      float p0 = __builtin_amdgcn_exp2f(v0a[r] - m_use);  // exp2(-huge)=0: mask free
      float p1 = __builtin_amdgcn_exp2f(v1a[r] - m_use);
      union { float f; unsigned u; } u0, u1;
      u0.f = p0; u1.f = p1;
      *(unsigned int*)((char*)Ps +
          ((qrow * 64 + lr * 4) ^ ((qrow & 7) << 4))) =
          (u0.u >> 16) | (u1.u & 0xFFFF0000u);  // RTZ pack, 3 VALU ops
      l_part[r] += p0 + p1;  // f32 partials; reduced once after the k-loop
    }

    // O += P V in permuted slot order (bijection over k: sum unchanged).
    // Ps rows wave-local: same-wave write->read, no barrier. One MFMA per f.
    __builtin_amdgcn_s_setprio(1);
    {
      int prow = 16 * w + lr;
      bf16x8 ap = *(const bf16x8*)((const char*)Ps +
                   ((prow * 64 + lg * 16) ^ ((prow & 7) << 4)));
      for (int f = 0; f < 8; ++f) {
        int vrow = f * 16 + lr;
        bf16x8 bv = *(const bf16x8*)(vb +
                     ((vrow * 64 + lg * 16) ^ ((vrow & 7) << 4)));
        o_acc[f] = __builtin_amdgcn_mfma_f32_16x16x32_bf16(ap, bv, o_acc[f], 0, 0, 0);
      }
    }
    __builtin_amdgcn_s_setprio(0);
  };

  // prologue: buf0 <- tile 0; regs <- tile 1
  load_tile(0);
  stage_tile((char*)Ks[0], (char*)Vs[0]);
  if (nt > 1) load_tile(1);
  asm volatile("s_waitcnt lgkmcnt(0)" ::: "memory");
  __builtin_amdgcn_s_barrier();
  __builtin_amdgcn_sched_barrier(0);

  for (int t = 0; t < nt; t += 2) {
    // phase A: current = buf0
    if (t + 1 < nt) stage_tile((char*)Ks[1], (char*)Vs[1]);
    if (t + 2 < nt) load_tile(t + 2);
    compute_tile(t, (const char*)Ks[0], (const char*)Vs[0]);
    asm volatile("s_waitcnt lgkmcnt(0)" ::: "memory");
    __builtin_amdgcn_s_barrier();
    __builtin_amdgcn_sched_barrier(0);
    if (t + 1 >= nt) break;  // nt even: never taken, keeps codegen honest
    // phase B: current = buf1
    if (t + 2 < nt) stage_tile((char*)Ks[0], (char*)Vs[0]);
    if (t + 3 < nt) load_tile(t + 3);
    compute_tile(t + 1, (const char*)Ks[1], (const char*)Vs[1]);
    asm volatile("s_waitcnt lgkmcnt(0)" ::: "memory");
    __builtin_amdgcn_s_barrier();
    __builtin_amdgcn_sched_barrier(0);
  }

  unsigned short* dst = AOb + ((size_t)b * SEQL + q0) * DMODEL + h * HDIM;
  for (int r = 0; r < 4; ++r) {
    float l = l_part[r];  // reduce the deferred row-sum partials (16-lane group)
    l += __shfl_xor(l, 1);
    l += __shfl_xor(l, 2);
    l += __shfl_xor(l, 4);
    l += __shfl_xor(l, 8);
    float inv = 1.0f / l;
    for (int f = 0; f < 8; ++f)
      dst[(size_t)(qrow_base + r) * DMODEL + f * 16 + lr] = f2bf(o_acc[f][r] * inv);
  }
}

extern "C" void kernel_launch(void* const* d_in, const int* in_sizes, int n_in,
                              void* d_out, int out_size, void* d_ws, size_t ws_size,
                              hipStream_t stream) {
  const float* hidden = (const float*)d_in[0];
  const float* cosb = (const float*)d_in[1];
  const float* sinb = (const float*)d_in[2];
  // d_in[3] = attention_mask: exactly causal triu(-1e9); equivalent to hard causal mask.
  const float* wq = (const float*)d_in[4];
  const float* wk = (const float*)d_in[5];
  const float* wv = (const float*)d_in[6];
  const float* wo = (const float*)d_in[7];
  const float* qw = (const float*)d_in[8];
  const float* kw = (const float*)d_in[9];
  float* out = (float*)d_out;

  char* ws = (char*)d_ws;
  // De-aliased layout (63MB total; previous champion used 79.7MB of ws):
  unsigned short* Xb    = (unsigned short*)(ws + 0);          // 4096x2048 bf16; reused as AOb
  unsigned short* Wqkvb = (unsigned short*)(ws + 16777216);   // 3072x2048 bf16
  unsigned short* Qbuf  = (unsigned short*)(ws + 29360128);   // (2,16,2048,128) bf16
  unsigned short* Kbuf  = (unsigned short*)(ws + 46137344);   // (2,4,2048,128) bf16
  unsigned short* Vtb   = (unsigned short*)(ws + 50331648);   // (2,4,128,2048) bf16, k-permuted
  unsigned short* Wob   = (unsigned short*)(ws + 54525952);   // 2048x2048 bf16 (own slot now)
  unsigned short* AOb   = Xb;    // X is dead after QKV GEMM

  // 1) casts (X, wq|wk|wv fused, wo — all independent now)
  cast_kernel<<<(8388608 / 8 + 255) / 256, 256, 0, stream>>>(hidden, Xb, 8388608 / 8);
  cast3_kernel<<<(786432 + 255) / 256, 256, 0, stream>>>(wq, wk, wv, Wqkvb,
                                                         524288, 131072, 131072);
  cast_kernel<<<(4194304 / 8 + 255) / 256, 256, 0, stream>>>(wo, Wob, 4194304 / 8);

  // 2) QKV GEMM with fused RMSNorm+RoPE+V^T epilogue (no QKVb round trip)
  gemm_qkv_fused<<<dim3(24, 32), 512, 0, stream>>>(Xb, Wqkvb, cosb, sinb, qw, kw,
                                                   Qbuf, Kbuf, Vtb);

  // 3) causal flash attention -> (B,L,2048) bf16. XCD-chunked bijection inside.
  flash_kernel<<<dim3(SEQL / 128, 2 * NH), 512, 0, stream>>>(Qbuf, Kbuf, Vtb, AOb);

  // 4) out = AO * Wo^T   (M=4096, N=2048, K=2048), f32 out. 8-wave, XCD-chunked.
  gemm_wo<<<dim3(2048 / 128, 4096 / 128), 512, 0, stream>>>(AOb, Wob, out, 4096, 2048, 2048);
}

// Round 29
// 197.732 us; speedup vs baseline: 1.1978x; 1.1978x over previous
//
#include <hip/hip_runtime.h>

// Qwen3 attention block, MI355X gfx950. FINAL CHAMPION configuration.
// Sizes fixed by the reference: B=2, L=2048, D=2048, H=16, KVH=4, HD=128.
// Pipeline: cast -> QKV GEMM (bf16 MFMA) -> RMSNorm+RoPE+V^T prep ->
//           causal flash attention (bf16 MFMA) -> output GEMM (f32 out).
//
// Session ladder: 360 -> 197.8us (r26, reproduced 199.0 r27). Flash: v7
// dbuf 100 -> v10 packed-P 98.6 -> v11 KT=32 86.4 -> v13 XCD-chunk 82.4
// (FETCH 33.9->12.3MB) -> v14 RTZ 79.5 -> v15 1-ballot 73.7us. GEMM: r8
// BK=64+both-sides-swizzle -> r26 8-wave (512thr, 2x4 waves, 64x32/wave)
// = thread-limited 32 waves/CU. prep: batched-butterfly + V k-perm.
// Closed spaces: GEMM sync-structure (r13 dbuf, r16 phase-split), GEMM
// locality (r23 neutral), flash LDS swizzle (b128 floor), flash V-from-
// global (r10), flash 32q/wave (r11), cvt_pk (r19/r20), prep-into-GEMM
// fusion (r28: epilogue tail exposed, 123us vs 79 split - REVERTED).
// HARD RULES: NEVER add a min-waves launch_bounds arg (r4/r7 force-spill).

#define SEQL 2048
#define DMODEL 2048
#define NH 16
#define NKVH 4
#define HDIM 128
#define SCALE_QK 0.08838834764831845f  // 1/sqrt(128)
#define LOG2E 1.4426950408889634f      // folded into Q so softmax uses exp2
#define INFF 3.0e38f

typedef __attribute__((ext_vector_type(8))) short bf16x8;
typedef __attribute__((ext_vector_type(4))) float f32x4;
typedef __attribute__((ext_vector_type(4))) unsigned int u32x4;

__device__ __forceinline__ unsigned short f2bf(float x) {
  union { float f; unsigned u; } v; v.f = x;
  unsigned r = v.u + 0x7fffu + ((v.u >> 16) & 1u);  // RNE
  return (unsigned short)(r >> 16);
}
__device__ __forceinline__ float bf2f(unsigned short u) {
  union { unsigned u; float f; } v; v.u = ((unsigned)u) << 16;
  return v.f;
}

// ---------------- f32 -> bf16 cast, 8 elems/thread ----------------
__global__ __launch_bounds__(256) void cast_kernel(const float* __restrict__ src,
                                                   unsigned short* __restrict__ dst,
                                                   int n8) {
  int i = blockIdx.x * 256 + threadIdx.x;
  if (i >= n8) return;
  const f32x4* s4 = (const f32x4*)src;
  f32x4 a = s4[2 * i], b = s4[2 * i + 1];
  union { unsigned short s[8]; u32x4 v; } o;
  o.s[0] = f2bf(a[0]); o.s[1] = f2bf(a[1]); o.s[2] = f2bf(a[2]); o.s[3] = f2bf(a[3]);
  o.s[4] = f2bf(b[0]); o.s[5] = f2bf(b[1]); o.s[6] = f2bf(b[2]); o.s[7] = f2bf(b[3]);
  ((u32x4*)dst)[i] = o.v;
}

// three sources -> one contiguous bf16 dst (wq|wk|wv), saves 2 launches
__global__ __launch_bounds__(256) void cast3_kernel(const float* __restrict__ s0,
                                                    const float* __restrict__ s1,
                                                    const float* __restrict__ s2,
                                                    unsigned short* __restrict__ dst,
                                                    int n0, int n1, int n2) {
  int i = blockIdx.x * 256 + threadIdx.x;  // units of 8 elems
  const float* src;
  int j;
  if (i < n0) { src = s0; j = i; }
  else if (i < n0 + n1) { src = s1; j = i - n0; }
  else if (i < n0 + n1 + n2) { src = s2; j = i - n0 - n1; }
  else return;
  const f32x4* s4 = (const f32x4*)src;
  f32x4 a = s4[2 * j], b = s4[2 * j + 1];
  union { unsigned short s[8]; u32x4 v; } o;
  o.s[0] = f2bf(a[0]); o.s[1] = f2bf(a[1]); o.s[2] = f2bf(a[2]); o.s[3] = f2bf(a[3]);
  o.s[4] = f2bf(b[0]); o.s[5] = f2bf(b[1]); o.s[6] = f2bf(b[2]); o.s[7] = f2bf(b[3]);
  ((u32x4*)dst)[i] = o.v;
}

// ---------------- GEMM: C[M,N] = A[M,K] * B[N,K]^T (bf16 in), 8-wave ---------
// r8 structure (128x128 tile, BK=64, 2-barrier/K-tile, both-sides swizzle,
// 32KB LDS) with 512 threads / 8 waves in 2x4; each wave owns 64x32 (acc
// 32 VGPR) -> 4 blocks/CU x 8 waves = 32 waves/CU (thread-limit max).
// + r23 XCD-chunked grid bijection (neutral, kept).
template <int OUT_BF16>
__global__ __launch_bounds__(512) void gemm_bt(const unsigned short* __restrict__ A,
                                               const unsigned short* __restrict__ B,
                                               void* __restrict__ C,
                                               int M, int N, int K) {
  __shared__ unsigned short As[128 * 64];  // 16KB, linear dest for global_load_lds
  __shared__ unsigned short Bs[128 * 64];  // 16KB
  int tid = threadIdx.x;
  int w = tid >> 6, lane = tid & 63;
  int lr = lane & 15, lg = lane >> 4;
  // XCD-chunked bijection (grid x = N/128 divisible by 8 at both call sites)
  int nx = N >> 7;
  int lid = (int)blockIdx.x + (int)blockIdx.y * nx;
  int chunk = nx >> 3;
  int xcd = lid & 7;
  int local = lid >> 3;
  int bx = chunk * xcd + local % chunk;
  int by = local / chunk;
  int m0 = by * 128, n0 = bx * 128;
  int wr = (w >> 2) * 64, wc = (w & 3) * 32;  // 2x4 wave grid, 64x32 per wave
  f32x4 zero4 = {0.f, 0.f, 0.f, 0.f};
  f32x4 acc[4][2];
  for (int i = 0; i < 4; ++i)
    for (int j = 0; j < 2; ++j) acc[i][j] = zero4;

  for (int k0 = 0; k0 < K; k0 += 64) {
    __syncthreads();  // all waves done reading previous tile
    // 512 threads stage 16KB per operand: 2 x 16B each
    for (int i = 0; i < 2; ++i) {
      int o = i * 8192 + tid * 16;              // linear byte offset in 16KB tile
      int row = o >> 7, cb = o & 127;           // 128B per row of 64 bf16
      int scb = cb ^ ((row & 7) << 4);          // inverse-swizzled source col
      const char* ga = (const char*)(A + (size_t)(m0 + row) * K + k0) + scb;
      const char* gb = (const char*)(B + (size_t)(n0 + row) * K + k0) + scb;
      __builtin_amdgcn_global_load_lds(
          (const __attribute__((address_space(1))) void*)ga,
          (__attribute__((address_space(3))) void*)((char*)As + i * 8192 + w * 1024),
          16, 0, 0);
      __builtin_amdgcn_global_load_lds(
          (const __attribute__((address_space(1))) void*)gb,
          (__attribute__((address_space(3))) void*)((char*)Bs + i * 8192 + w * 1024),
          16, 0, 0);
    }
    asm volatile("s_waitcnt vmcnt(0)" ::: "memory");
    __syncthreads();

    for (int kk = 0; kk < 2; ++kk) {
      bf16x8 a[4], b[2];
      for (int i = 0; i < 4; ++i) {
        int row = wr + i * 16 + lr;
        int col = kk * 64 + lg * 16;  // byte col within row
        a[i] = *(const bf16x8*)((const char*)As + row * 128 + (col ^ ((row & 7) << 4)));
      }
      for (int j = 0; j < 2; ++j) {
        int row = wc + j * 16 + lr;
        int col = kk * 64 + lg * 16;
        b[j] = *(const bf16x8*)((const char*)Bs + row * 128 + (col ^ ((row & 7) << 4)));
      }
      for (int i = 0; i < 4; ++i)
        for (int j = 0; j < 2; ++j)
          acc[i][j] = __builtin_amdgcn_mfma_f32_16x16x32_bf16(a[i], b[j], acc[i][j], 0, 0, 0);
    }
  }

  // C/D layout: col = lane&15, row = (lane>>4)*4 + reg   (verified m89/m91)
  for (int i = 0; i < 4; ++i)
    for (int j = 0; j < 2; ++j) {
      int row = m0 + wr + i * 16 + lg * 4;
      int col = n0 + wc + j * 16 + lr;
      for (int r = 0; r < 4; ++r) {
        if (OUT_BF16)
          ((unsigned short*)C)[(size_t)(row + r) * N + col] = f2bf(acc[i][j][r]);
        else
          ((float*)C)[(size_t)(row + r) * N + col] = acc[i][j][r];
      }
    }
}

// ---------------- RMSNorm + RoPE + V transpose, v4 ----------------
// One wave per (b,l); batched butterfly reduce (r12). V^T store PERMUTES the
// seq index within each 32-block: slot sigma32(k)=2*(k&15)+(k>>4), matching
// flash's packed-P ds_write_b32 slot order (PV sums over a k-bijection).
__global__ __launch_bounds__(64) void prep_kernel(const unsigned short* __restrict__ qkv,
                                                  const float* __restrict__ cosb,
                                                  const float* __restrict__ sinb,
                                                  const float* __restrict__ qw,
                                                  const float* __restrict__ kw,
                                                  unsigned short* __restrict__ Qb,   // (B,NH,L,HD)
                                                  unsigned short* __restrict__ Kb,   // (B,NKVH,L,HD)
                                                  unsigned short* __restrict__ Vtb)  // (B,NKVH,HD,L) k-permuted
{
  int l = blockIdx.x, b = blockIdx.y, d = threadIdx.x;  // d in [0,64)
  size_t row = (size_t)b * SEQL + l;
  const unsigned short* src = qkv + row * 3072;
  float c0 = cosb[row * HDIM + d], c1 = cosb[row * HDIM + d + 64];
  float s0 = sinb[row * HDIM + d], s1 = sinb[row * HDIM + d + 64];
  float qw0 = qw[d], qw1 = qw[d + 64];
  float kw0 = kw[d], kw1 = kw[d + 64];
  const float qscale = SCALE_QK * LOG2E;

  float x0[20], x1[20], ss[20];
#pragma unroll
  for (int h = 0; h < 20; ++h) {
    x0[h] = bf2f(src[h * HDIM + d]);
    x1[h] = bf2f(src[h * HDIM + d + 64]);
    ss[h] = x0[h] * x0[h] + x1[h] * x1[h];
  }
#pragma unroll
  for (int m = 1; m < 64; m <<= 1) {
#pragma unroll
    for (int h = 0; h < 20; ++h) ss[h] += __shfl_xor(ss[h], m);
  }
#pragma unroll
  for (int h = 0; h < 16; ++h) {
    float inv = rsqrtf(ss[h] * (1.0f / 128.0f) + 1e-6f);
    float n0 = x0[h] * inv * qw0, n1 = x1[h] * inv * qw1;
    float r0 = (n0 * c0 - n1 * s0) * qscale;
    float r1 = (n1 * c1 + n0 * s1) * qscale;
    unsigned short* dst = Qb + (((size_t)(b * NH + h)) * SEQL + l) * HDIM;
    dst[d] = f2bf(r0);
    dst[d + 64] = f2bf(r1);
  }
#pragma unroll
  for (int h = 0; h < 4; ++h) {
    float inv = rsqrtf(ss[16 + h] * (1.0f / 128.0f) + 1e-6f);
    float n0 = x0[16 + h] * inv * kw0, n1 = x1[16 + h] * inv * kw1;
    float r0 = n0 * c0 - n1 * s0;
    float r1 = n1 * c1 + n0 * s1;
    unsigned short* dst = Kb + (((size_t)(b * NKVH + h)) * SEQL + l) * HDIM;
    dst[d] = f2bf(r0);
    dst[d + 64] = f2bf(r1);
  }
  // V^T with k-permutation within each 32-block
  int lt = l & 31, lb = l & ~31;
  int lp = lb + 2 * (lt & 15) + (lt >> 4);  // sigma32(local k)
#pragma unroll
  for (int h = 0; h < NKVH; ++h) {
    unsigned short v0 = src[2560 + h * HDIM + d];
    unsigned short v1 = src[2560 + h * HDIM + d + 64];
    unsigned short* dst = Vtb + ((size_t)(b * NKVH + h) * HDIM) * SEQL;
    dst[(size_t)d * SEQL + lp] = v0;
    dst[(size_t)(d + 64) * SEQL + lp] = v1;
  }
}

// ---------------- causal flash attention, v15 (CHAMPION, 73.7us) -------------
// KT=32 dbuf, ONE barrier/tile, T14 prefetch, zero-crosslane common-path
// softmax, exp2 + T13 THR=8, T2 swizzle, setprio, RTZ P-pack, 1-ballot
// defer-max gate, LDS 40KB, XCD-chunked grid (FETCH 12.3MB).
// NO min-waves hint ever (r4/r7 force-spills).
__global__ __launch_bounds__(512) void flash_kernel(const unsigned short* __restrict__ Qb,
                                                    const unsigned short* __restrict__ Kb,
                                                    const unsigned short* __restrict__ Vtb,
                                                    unsigned short* __restrict__ AOb)
{
  __shared__ unsigned short Ks[2][32 * 128];   // [buf][k][d], swizzled (8KB each)
  __shared__ unsigned short Vs[2][128 * 32];   // [buf][hd][k-slot], swizzled (8KB each)
  __shared__ unsigned short Ps[128 * 32];      // [q][k-slot], swizzled (8KB)

  int tid = threadIdx.x, w = tid >> 6, lane = tid & 63;
  int lr = lane & 15, lg = lane >> 4;
  int lid = (int)blockIdx.x + ((int)blockIdx.y << 4);  // 0..511
  int work = ((lid & 7) << 6) | (lid >> 3);            // XCD-chunked bijection
  int bh = work >> 4;
  int xi = work & 15;
  int qt = ((work >> 5) & 1) ? 15 - xi : xi;           // anti-correlated pairs
  int b = bh >> 4, h = bh & 15, hk = h >> 2;  // GROUPS=4
  int q0 = qt * 128;
  int qrow_base = 16 * w + lg * 4;

  // Q fragments: wave-private 16 rows, held in registers
  const unsigned short* Qg =
      Qb + (((size_t)(b * NH + h)) * SEQL + q0 + 16 * w + lr) * HDIM + lg * 8;
  bf16x8 aq[4];
  for (int kk = 0; kk < 4; ++kk) aq[kk] = *(const bf16x8*)(Qg + kk * 32);

  const unsigned short* Kg0 = Kb + ((size_t)(b * NKVH + hk)) * SEQL * HDIM;
  const unsigned short* Vg0 = Vtb + ((size_t)(b * NKVH + hk)) * HDIM * SEQL;

  float m_run[4], l_part[4];
  f32x4 zero4 = {0.f, 0.f, 0.f, 0.f};
  f32x4 o_acc[8];
  for (int r = 0; r < 4; ++r) { m_run[r] = -INFF; l_part[r] = 0.f; }
  for (int f = 0; f < 8; ++f) o_acc[f] = zero4;

  int nt = 4 * (qt + 1);  // 32-key tiles; always multiple of 4 (even)

  // reg staging: 1x16B K + 1x16B V per thread per tile (512 thr x 16B = 8KB)
  u32x4 kr, vr;

  auto load_tile = [&](int tt) {
    int k0n = tt * 32;
    int o = tid * 16;
    kr = *(const u32x4*)((const char*)Kg0 + (size_t)(k0n + (o >> 8)) * 256 + (o & 255));
    vr = *(const u32x4*)((const char*)Vg0 +
                         (size_t)(o >> 6) * (SEQL * 2) + (size_t)k0n * 2 + (o & 63));
  };
  auto stage_tile = [&](char* kb, char* vb) {
    int o = tid * 16;
    int krow = o >> 8;
    *(u32x4*)(kb + (o ^ ((krow & 7) << 4))) = kr;
    int vrow = o >> 6;
    *(u32x4*)(vb + (o ^ ((vrow & 7) << 4))) = vr;
  };
  auto compute_tile = [&](int t, const char* kb, const char* vb) {
    int k0 = t * 32;
    if (k0 > q0 + 16 * w + 15) return;  // fully masked for this wave
    bool needmask = (k0 + 31 > q0 + 16 * w);

    // S = Q K^T  (s[j][r] = S[q=qrow_base+r][k = 16j+lr])
    f32x4 s[2];
    for (int j = 0; j < 2; ++j) s[j] = zero4;
    __builtin_amdgcn_s_setprio(1);
    for (int kk = 0; kk < 4; ++kk)
      for (int j = 0; j < 2; ++j) {
        int row = j * 16 + lr;
        bf16x8 bk = *(const bf16x8*)(kb +
                     ((row * 256 + kk * 64 + lg * 16) ^ ((lr & 7) << 4)));
        s[j] = __builtin_amdgcn_mfma_f32_16x16x32_bf16(aq[kk], bk, s[j], 0, 0, 0);
      }
    __builtin_amdgcn_s_setprio(0);

    // online softmax, exp2 domain. Masked values, per-row local maxima.
    float v0a[4], v1a[4], mxl[4];
    float gmax = -INFF;
    for (int r = 0; r < 4; ++r) {
      if (needmask) {
        int qg = q0 + qrow_base + r;
        v0a[r] = (k0 + lr <= qg) ? s[0][r] : -INFF;
        v1a[r] = (k0 + 16 + lr <= qg) ? s[1][r] : -INFF;
      } else {
        v0a[r] = s[0][r];
        v1a[r] = s[1][r];
      }
      mxl[r] = fmaxf(v0a[r], v1a[r]);
      gmax = fmaxf(gmax, mxl[r] - m_run[r]);  // growth, per lane, max over rows
    }
    // ONE wave-wide ballot per tile; rescale body self-corrects per row
    if (!__all(gmax <= 8.f)) {  // rare: some row grew > THR
      for (int r = 0; r < 4; ++r) {
        float mx = mxl[r];
        mx = fmaxf(mx, __shfl_xor(mx, 1));
        mx = fmaxf(mx, __shfl_xor(mx, 2));
        mx = fmaxf(mx, __shfl_xor(mx, 4));
        mx = fmaxf(mx, __shfl_xor(mx, 8));
        float m_new = fmaxf(m_run[r], mx);
        float sc = __builtin_amdgcn_exp2f(m_run[r] - m_new);
        l_part[r] *= sc;
        for (int f = 0; f < 8; ++f) o_acc[f][r] *= sc;
        m_run[r] = m_new;
      }
    }
    for (int r = 0; r < 4; ++r) {
      int qrow = qrow_base + r;
      float m_use = m_run[r];
      float p0 = __builtin_amdgcn_exp2f(v0a[r] - m_use);  // exp2(-huge)=0: mask free
      float p1 = __builtin_amdgcn_exp2f(v1a[r] - m_use);
      union { float f; unsigned u; } u0, u1;
      u0.f = p0; u1.f = p1;
      *(unsigned int*)((char*)Ps +
          ((qrow * 64 + lr * 4) ^ ((qrow & 7) << 4))) =
          (u0.u >> 16) | (u1.u & 0xFFFF0000u);  // RTZ pack, 3 VALU ops
      l_part[r] += p0 + p1;  // f32 partials; reduced once after the k-loop
    }

    // O += P V in permuted slot order (bijection over k: sum unchanged).
    // Ps rows wave-local: same-wave write->read, no barrier. One MFMA per f.
    __builtin_amdgcn_s_setprio(1);
    {
      int prow = 16 * w + lr;
      bf16x8 ap = *(const bf16x8*)((const char*)Ps +
                   ((prow * 64 + lg * 16) ^ ((prow & 7) << 4)));
      for (int f = 0; f < 8; ++f) {
        int vrow = f * 16 + lr;
        bf16x8 bv = *(const bf16x8*)(vb +
                     ((vrow * 64 + lg * 16) ^ ((vrow & 7) << 4)));
        o_acc[f] = __builtin_amdgcn_mfma_f32_16x16x32_bf16(ap, bv, o_acc[f], 0, 0, 0);
      }
    }
    __builtin_amdgcn_s_setprio(0);
  };

  // prologue: buf0 <- tile 0; regs <- tile 1
  load_tile(0);
  stage_tile((char*)Ks[0], (char*)Vs[0]);
  if (nt > 1) load_tile(1);
  asm volatile("s_waitcnt lgkmcnt(0)" ::: "memory");
  __builtin_amdgcn_s_barrier();
  __builtin_amdgcn_sched_barrier(0);

  for (int t = 0; t < nt; t += 2) {
    // phase A: current = buf0
    if (t + 1 < nt) stage_tile((char*)Ks[1], (char*)Vs[1]);
    if (t + 2 < nt) load_tile(t + 2);
    compute_tile(t, (const char*)Ks[0], (const char*)Vs[0]);
    asm volatile("s_waitcnt lgkmcnt(0)" ::: "memory");
    __builtin_amdgcn_s_barrier();
    __builtin_amdgcn_sched_barrier(0);
    if (t + 1 >= nt) break;  // nt even: never taken, keeps codegen honest
    // phase B: current = buf1
    if (t + 2 < nt) stage_tile((char*)Ks[0], (char*)Vs[0]);
    if (t + 3 < nt) load_tile(t + 3);
    compute_tile(t + 1, (const char*)Ks[1], (const char*)Vs[1]);
    asm volatile("s_waitcnt lgkmcnt(0)" ::: "memory");
    __builtin_amdgcn_s_barrier();
    __builtin_amdgcn_sched_barrier(0);
  }

  unsigned short* dst = AOb + ((size_t)b * SEQL + q0) * DMODEL + h * HDIM;
  for (int r = 0; r < 4; ++r) {
    float l = l_part[r];  // reduce the deferred row-sum partials (16-lane group)
    l += __shfl_xor(l, 1);
    l += __shfl_xor(l, 2);
    l += __shfl_xor(l, 4);
    l += __shfl_xor(l, 8);
    float inv = 1.0f / l;
    for (int f = 0; f < 8; ++f)
      dst[(size_t)(qrow_base + r) * DMODEL + f * 16 + lr] = f2bf(o_acc[f][r] * inv);
  }
}

extern "C" void kernel_launch(void* const* d_in, const int* in_sizes, int n_in,
                              void* d_out, int out_size, void* d_ws, size_t ws_size,
                              hipStream_t stream) {
  const float* hidden = (const float*)d_in[0];
  const float* cosb = (const float*)d_in[1];
  const float* sinb = (const float*)d_in[2];
  // d_in[3] = attention_mask: exactly causal triu(-1e9); equivalent to hard causal mask.
  const float* wq = (const float*)d_in[4];
  const float* wk = (const float*)d_in[5];
  const float* wv = (const float*)d_in[6];
  const float* wo = (const float*)d_in[7];
  const float* qw = (const float*)d_in[8];
  const float* kw = (const float*)d_in[9];
  float* out = (float*)d_out;

  char* ws = (char*)d_ws;
  unsigned short* Xb    = (unsigned short*)(ws + 0);          // 4096x2048 bf16; reused as AOb
  unsigned short* Wqkvb = (unsigned short*)(ws + 16777216);   // 3072x2048 bf16
  unsigned short* QKVb  = (unsigned short*)(ws + 29360128);   // 4096x3072 bf16; reused as Wob
  unsigned short* Qbuf  = (unsigned short*)(ws + 54525952);   // (2,16,2048,128) bf16
  unsigned short* Kbuf  = (unsigned short*)(ws + 71303168);   // (2,4,2048,128) bf16
  unsigned short* Vtb   = (unsigned short*)(ws + 75497472);   // (2,4,128,2048) bf16, k-permuted
  unsigned short* AOb   = Xb;    // X is dead after QKV GEMM
  unsigned short* Wob   = QKVb;  // QKV is dead after prep

  // 1) casts (X, and wq|wk|wv fused into one launch)
  cast_kernel<<<(8388608 / 8 + 255) / 256, 256, 0, stream>>>(hidden, Xb, 8388608 / 8);
  cast3_kernel<<<(786432 + 255) / 256, 256, 0, stream>>>(wq, wk, wv, Wqkvb,
                                                         524288, 131072, 131072);

  // 2) QKV = X * Wqkv^T   (M=4096, N=3072, K=2048), bf16 out. 8-wave, XCD-chunked.
  gemm_bt<1><<<dim3(3072 / 128, 4096 / 128), 512, 0, stream>>>(Xb, Wqkvb, QKVb, 4096, 3072, 2048);

  // 3) RMSNorm + RoPE + V transpose (Q pre-scaled by SCALE_QK*log2e; V k-permuted per 32)
  prep_kernel<<<dim3(SEQL, 2), 64, 0, stream>>>(QKVb, cosb, sinb, qw, kw, Qbuf, Kbuf, Vtb);

  // wo cast into QKV's (now dead) space — must stay AFTER prep (aliases QKVb)
  cast_kernel<<<(4194304 / 8 + 255) / 256, 256, 0, stream>>>(wo, Wob, 4194304 / 8);

  // 4) causal flash attention -> (B,L,2048) bf16. XCD-chunked bijection inside.
  flash_kernel<<<dim3(SEQL / 128, 2 * NH), 512, 0, stream>>>(Qbuf, Kbuf, Vtb, AOb);

  // 5) out = AO * Wo^T   (M=4096, N=2048, K=2048), f32 out. 8-wave, XCD-chunked.
  gemm_bt<0><<<dim3(2048 / 128, 4096 / 128), 512, 0, stream>>>(AOb, Wob, out, 4096, 2048, 2048);
}